// Round 10
// baseline (247.077 us; speedup 1.0000x reference)
//
#include <hip/hip_runtime.h>
#include <math.h>

// Problem constants
#define BB 2
#define CC 128
#define NN 4096            // D*H*W = 16*16*16
#define EE 46              // 16 + 15 + 15 neighbors
#define EH 23              // EE/2 per e-half block
#define DS 64              // DSIM = PSIM = GDIM = 64
#define CPAD 16            // dwords per colnorm counter (one 64B line each)

// ===========================================================================
// Setup: zero colnorms, neighbor table, geo projections, h transpose.
// grid 512 x 256.
__global__ __launch_bounds__(256) void k_setup(
    const float* __restrict__ x,
    const float* __restrict__ gt_w, const float* __restrict__ gt_b,
    const float* __restrict__ gp_w, const float* __restrict__ gp_b,
    int* __restrict__ nbr, float* __restrict__ p_theta, float* __restrict__ p_phi,
    float* __restrict__ colnorm_p, float* __restrict__ colnorm_f,
    float* __restrict__ h)
{
    __shared__ float xs[32 * 65];
    const int t = threadIdx.x, bid = blockIdx.x;
    const int gtid = bid * 256 + t;

    if (gtid < EE * CPAD) colnorm_p[gtid] = 0.f;
    if (gtid < 3 * BB * EE * CPAD) colnorm_f[gtid] = 0.f;

    if (gtid < NN) {   // sorted 3-way merge of axis neighbor lists
        int n = gtid;
        int i = n >> 8, j = (n >> 4) & 15, k = n & 15;
        int ia = 0, ib = 0, ic = 0;
        for (int e = 0; e < EE; ++e) {
            int va = (ia < 16) ? ia * 256 + j * 16 + k : 0x7fffffff;
            int jb = ib + (ib >= j ? 1 : 0);
            int vb = (ib < 15) ? i * 256 + jb * 16 + k : 0x7fffffff;
            int kc = ic + (ic >= k ? 1 : 0);
            int vc = (ic < 15) ? i * 256 + j * 16 + kc : 0x7fffffff;
            int v;
            if (va < vb && va < vc)      { v = va; ++ia; }
            else if (vb < vc)            { v = vb; ++ib; }
            else                         { v = vc; ++ic; }
            nbr[n * EE + e] = v;
        }
    }
    for (int idx = gtid; idx < NN * DS; idx += 512 * 256) {
        int n = idx >> 6, s = idx & 63;
        int i = n >> 8, j = (n >> 4) & 15, k = n & 15;
        float p0 = i * (1.f / 15.f) - 0.5f;
        float p1 = j * (1.f / 15.f) - 0.5f;
        float p2 = k * (1.f / 15.f) - 0.5f;
        p_theta[idx] = p0 * gt_w[s * 3] + p1 * gt_w[s * 3 + 1] + p2 * gt_w[s * 3 + 2] + gt_b[s];
        p_phi[idx]   = p0 * gp_w[s * 3] + p1 * gp_w[s * 3 + 1] + p2 * gp_w[s * 3 + 2] + gp_b[s];
    }
    {   // h[b][n][c] = x[b][c][n], one 64n x 32c tile per block
        int n0 = (bid & 63) * 64, c0 = ((bid >> 6) & 3) * 32, b = bid >> 8;
        for (int q = t; q < 2048; q += 256) {
            int cl = q >> 6, nl = q & 63;
            xs[cl * 65 + nl] = x[(size_t)(b * CC + c0 + cl) * NN + n0 + nl];
        }
        __syncthreads();
        for (int q = t; q < 2048; q += 256) {
            int nl = q >> 5, cl = q & 31;
            h[(size_t)(b * NN + n0 + nl) * CC + c0 + cl] = xs[cl * 65 + nl];
        }
    }
}

// ===========================================================================
// proj: [8192x128]x[128x192]^T GEMM. 32-row x 64-col tiles, BOTH operands
// LDS-staged (48 KB -> 3 blocks/CU), XOR-swizzled, 2x4 register blocking.
// Blocks >=768 (round-0 launch only): one-time geo f_p dots + colnorm_p.
__global__ __launch_bounds__(256) void k_proj(
    const float* __restrict__ h,
    const float* __restrict__ th_w, const float* __restrict__ th_b,
    const float* __restrict__ ph_w, const float* __restrict__ ph_b,
    const float* __restrict__ G_w,  const float* __restrict__ G_b,
    float* __restrict__ T, float* __restrict__ P, float* __restrict__ Gx,
    const int* __restrict__ nbr,
    const float* __restrict__ p_theta, const float* __restrict__ p_phi,
    float* __restrict__ f_p, float* __restrict__ colnorm_p)
{
    __shared__ __align__(16) float smf[12288];   // 48 KB
    const int t = threadIdx.x;
    if (blockIdx.x < 768) {
        const int row0 = (blockIdx.x & 255) * 32;
        const int cgp = blockIdx.x >> 8;
        const float* w    = cgp == 0 ? th_w : cgp == 1 ? ph_w : G_w;
        const float* bias = cgp == 0 ? th_b : cgp == 1 ? ph_b : G_b;
        float* o          = cgp == 0 ? T    : cgp == 1 ? P    : Gx;
        float4* hs4 = (float4*)smf;              // [32][32] f4, XOR-swizzled
        float4* ws4 = (float4*)smf + 1024;       // [64][32] f4, XOR-swizzled
        const float4* h4 = (const float4*)h;
        const float4* w4 = (const float4*)w;
        for (int q = t; q < 1024; q += 256) {
            int row = q >> 5, kc = q & 31;
            hs4[row * 32 + (kc ^ row)] = h4[(size_t)(row0 + row) * 32 + kc];
        }
        for (int q = t; q < 2048; q += 256) {
            int row = q >> 5, kc = q & 31;
            ws4[row * 32 + (kc ^ (row & 31))] = w4[q];
        }
        __syncthreads();
        const int rt = t >> 4, m = t & 15;       // rows 2rt,2rt+1; cols m+16i
        float acc[2][4] = {{0, 0, 0, 0}, {0, 0, 0, 0}};
        for (int kc = 0; kc < 32; ++kc) {
            float4 a0 = hs4[(2 * rt) * 32 + (kc ^ (2 * rt))];
            float4 a1 = hs4[(2 * rt + 1) * 32 + (kc ^ (2 * rt + 1))];
            float4 wv[4];
#pragma unroll
            for (int i = 0; i < 4; ++i) {
                int c = m + 16 * i;
                wv[i] = ws4[c * 32 + (kc ^ (c & 31))];
            }
#pragma unroll
            for (int i = 0; i < 4; ++i) {
                acc[0][i] += a0.x * wv[i].x + a0.y * wv[i].y
                           + a0.z * wv[i].z + a0.w * wv[i].w;
                acc[1][i] += a1.x * wv[i].x + a1.y * wv[i].y
                           + a1.z * wv[i].z + a1.w * wv[i].w;
            }
        }
#pragma unroll
        for (int i = 0; i < 4; ++i) {
            float bv = bias[m + 16 * i];
#pragma unroll
            for (int rr = 0; rr < 2; ++rr)
                o[(size_t)(row0 + 2 * rt + rr) * DS + m + 16 * i] = acc[rr][i] + bv;
        }
    } else {
        // geo f_p: tile = blockIdx.x - 768 (b implicit 0, batch-identical)
        const int tile = blockIdx.x - 768;
        float4* ts4 = (float4*)smf;          // [16][17] f4  (dw 0..1087)
        int*    nbs = (int*)(smf + 1088);    // 736 ints
        float*  fvs = smf + 1824;            // 736 floats
        {
            int node = t >> 4, kc = t & 15;
            ts4[node * 17 + kc] =
                ((const float4*)p_theta)[(size_t)(tile * 16 + node) * 16 + kc];
        }
        for (int i2 = t; i2 < 16 * EE; i2 += 256) nbs[i2] = nbr[tile * 16 * EE + i2];
        __syncthreads();
        const int g = t >> 4, kc = t & 15;
        const float4 av = ts4[g * 17 + kc];
        const float4* P4 = (const float4*)p_phi;
        for (int e = 0; e < EE; ++e) {
            int m = nbs[g * EE + e];
            float4 p = P4[(size_t)m * 16 + kc];
            float v = av.x * p.x + av.y * p.y + av.z * p.z + av.w * p.w;
            v += __shfl_xor(v, 1);
            v += __shfl_xor(v, 2);
            v += __shfl_xor(v, 4);
            v += __shfl_xor(v, 8);
            if (kc == 0) {
                f_p[(size_t)(tile * 16 + g) * EE + e] = v;
                fvs[e * 16 + g] = v;
            }
        }
        __syncthreads();
        if (t < EE) {
            float s = 0.f;
#pragma unroll
            for (int q = 0; q < 16; ++q) { float v = fvs[t * 16 + q]; s += v * v; }
            atomicAdd(colnorm_p + t * CPAD, s);
        }
    }
}

// ===========================================================================
// k_f: f[b][n][e] = dot64(T[b,n], P[b,nbr[n,e]]) for one (tile, e-half, b).
// grid (256, 2, BB) = 1024 blocks (round-7 proven geometry). 16 groups of 16
// lanes: group = node, lane = float4 chunk (coalesced 256 B row per gather).
__global__ __launch_bounds__(256) void k_f(
    const int* __restrict__ nbr,
    const float* __restrict__ T, const float* __restrict__ P,
    float* __restrict__ f, float* __restrict__ colnorm)
{
    __shared__ __align__(16) float smf[2560];
    float4* ts4 = (float4*)smf;            // [16][17] f4  (dw 0..1087)
    int*    nbs = (int*)(smf + 1088);      // 736 ints
    float*  fvs = smf + 1824;              // [EH][16] floats

    const int t = threadIdx.x;
    const int tile = blockIdx.x, half = blockIdx.y, b = blockIdx.z;
    const int n0 = tile * 16, e0 = half * EH;
    {
        int node = t >> 4, kc = t & 15;
        ts4[node * 17 + kc] =
            ((const float4*)T)[(size_t)(b * NN + n0 + node) * 16 + kc];
    }
    for (int i2 = t; i2 < 16 * EE; i2 += 256) nbs[i2] = nbr[n0 * EE + i2];
    __syncthreads();

    const int g = t >> 4, kc = t & 15;
    const float4 av = ts4[g * 17 + kc];
    const float4* P4 = (const float4*)P;
    for (int ee = 0; ee < EH; ++ee) {
        int m = nbs[g * EE + e0 + ee];
        float4 p = P4[((size_t)b * NN + m) * 16 + kc];
        float v = av.x * p.x + av.y * p.y + av.z * p.z + av.w * p.w;
        v += __shfl_xor(v, 1);
        v += __shfl_xor(v, 2);
        v += __shfl_xor(v, 4);
        v += __shfl_xor(v, 8);
        if (kc == 0) fvs[ee * 16 + g] = v;
    }
    __syncthreads();

    for (int i = t; i < 16 * EH; i += 256) {
        int nl = i / EH, ee = i - nl * EH;
        f[(size_t)(b * NN + n0 + nl) * EE + e0 + ee] = fvs[ee * 16 + nl];
    }
    if (t < EH) {
        float s = 0.f;
#pragma unroll
        for (int q = 0; q < 16; ++q) { float v = fvs[t * 16 + q]; s += v * v; }
        atomicAdd(colnorm + (b * EE + e0 + t) * CPAD, s);
    }
}

// ===========================================================================
// k_attn: per (b, 16-node tile), 512 blocks. Softmax weights parked in LDS;
// gather loop FULLY UNROLLED with 4 independent load streams and LDS-broadcast
// addresses (no ds_bpermute in the loop -> many L2 gathers in flight).
// r_w LDS-staged rotation-swizzled (direct global reads were 32 lines/instr).
// LAST=1: write transposed out directly.
template <int LAST>
__global__ __launch_bounds__(256) void k_attn(
    const int* __restrict__ nbr,
    const float* __restrict__ f, const float* __restrict__ f_p,
    const float* __restrict__ colnorm_p, const float* __restrict__ colnorm_f,
    const float* __restrict__ Gx,
    const float* __restrict__ r_w, const float* __restrict__ r_b,
    float* __restrict__ h, float* __restrict__ out)
{
    __shared__ __align__(16) float smf[10784];   // 43136 B
    float4* rws4 = (float4*)smf;                 // [128][16] f4 rot-swz (dw 0..8191)
    float*  ys   = smf + 8192;                   // [16][68]  (dw 8192..9279)
    float*  ats  = smf + 9280;                   // [16][48]  (dw 9280..10047)
    int*    nbs  = (int*)(smf + 10048);          // [16][46] ints

    const int t = threadIdx.x;
    const int u = blockIdx.x;                    // 0..511
    const int b = u >> 8, tile = u & 255, n0 = tile * 16;

    for (int i2 = t; i2 < 2048; i2 += 256) {
        int c = i2 >> 4, g4 = i2 & 15;
        rws4[c * 16 + ((g4 + c) & 15)] = ((const float4*)r_w)[i2];
    }
    for (int i2 = t; i2 < 16 * EE; i2 += 256) nbs[i2] = nbr[(size_t)n0 * EE + i2];
    __syncthreads();

    // ---- softmax per node (4 waves x 4 nodes), weights -> LDS --------------
    const int wv = t >> 6, l = t & 63;
    float nf_inv = 0.f, np_inv = 0.f;
    if (l < EE) {
        nf_inv = 1.f / (1e-6f + sqrtf(colnorm_f[(b * EE + l) * CPAD]));
        np_inv = 1.f / (1e-6f + sqrtf(colnorm_p[l * CPAD]));
    }
    for (int ii = 0; ii < 4; ++ii) {
        int nl = wv * 4 + ii;
        int n = n0 + nl;
        float fvv = -INFINITY;
        if (l < EE) {
            float fpv = f_p[(size_t)n * EE + l] * np_inv;
            fpv = fpv > 0.f ? fpv : 0.f;
            fvv = f[(size_t)(b * NN + n) * EE + l] * nf_inv + fpv;
        }
        float mx = fvv;
        for (int o = 32; o; o >>= 1) mx = fmaxf(mx, __shfl_down(mx, o));
        mx = __shfl(mx, 0);
        float ex = (l < EE) ? expf(fvv - mx) : 0.f;
        float sm = ex;
        for (int o = 32; o; o >>= 1) sm += __shfl_down(sm, o);
        sm = __shfl(sm, 0);
        if (l < EE) ats[nl * 48 + l] = ex / sm;
    }
    __syncthreads();

    // ---- gather: wave handles 4 nodes, 2 at a time, 4 accumulator streams --
    const float* Gb = Gx + (size_t)b * NN * DS;
    for (int pp = 0; pp < 2; ++pp) {
        const int na = wv * 4 + pp * 2, nc = na + 1;
        float ya0 = 0.f, ya1 = 0.f, yc0 = 0.f, yc1 = 0.f;
#pragma unroll
        for (int e = 0; e < EE; e += 2) {
            float a0 = ats[na * 48 + e], a1 = ats[na * 48 + e + 1];
            float c0 = ats[nc * 48 + e], c1 = ats[nc * 48 + e + 1];
            int   m0 = nbs[na * EE + e], m1 = nbs[na * EE + e + 1];
            int   q0 = nbs[nc * EE + e], q1 = nbs[nc * EE + e + 1];
            ya0 += a0 * Gb[(size_t)m0 * DS + l];
            ya1 += a1 * Gb[(size_t)m1 * DS + l];
            yc0 += c0 * Gb[(size_t)q0 * DS + l];
            yc1 += c1 * Gb[(size_t)q1 * DS + l];
        }
        ys[na * 68 + l] = ya0 + ya1;
        ys[nc * 68 + l] = yc0 + yc1;
    }
    __syncthreads();

    // ---- epilogue: delta[16][128] = y[16][64] @ rw[128][64]^T (LDS rw) -----
    const int r0 = (t >> 5) * 2, cl = t & 31;
    float4* ys4 = (float4*)ys;                   // row stride 17 f4
    float acc[2][4] = {{0, 0, 0, 0}, {0, 0, 0, 0}};
    for (int g4 = 0; g4 < 16; ++g4) {
        float4 ya = ys4[r0 * 17 + g4];
        float4 yb = ys4[(r0 + 1) * 17 + g4];
#pragma unroll
        for (int cc = 0; cc < 4; ++cc) {
            int c = cl + 32 * cc;
            float4 w = rws4[c * 16 + ((g4 + c) & 15)];
            acc[0][cc] += ya.x * w.x + ya.y * w.y + ya.z * w.z + ya.w * w.w;
            acc[1][cc] += yb.x * w.x + yb.y * w.y + yb.z * w.z + yb.w * w.w;
        }
    }
#pragma unroll
    for (int rr = 0; rr < 2; ++rr) {
        int n = n0 + r0 + rr;
        size_t bn = (size_t)b * NN + n;
#pragma unroll
        for (int cc = 0; cc < 4; ++cc) {
            int c = cl + 32 * cc;
            float val = h[bn * CC + c] + acc[rr][cc] + r_b[c];
            if (LAST) out[(size_t)(b * CC + c) * NN + n] = val;
            else      h[bn * CC + c] = val;
        }
    }
}

// ===========================================================================
extern "C" void kernel_launch(void* const* d_in, const int* in_sizes, int n_in,
                              void* d_out, int out_size, void* d_ws, size_t ws_size,
                              hipStream_t stream) {
    const float* x    = (const float*)d_in[0];
    const float* G_w  = (const float*)d_in[1];
    const float* G_b  = (const float*)d_in[2];
    const float* th_w = (const float*)d_in[3];
    const float* th_b = (const float*)d_in[4];
    const float* ph_w = (const float*)d_in[5];
    const float* ph_b = (const float*)d_in[6];
    const float* r_w  = (const float*)d_in[7];
    const float* r_b  = (const float*)d_in[8];
    const float* gt_w = (const float*)d_in[9];
    const float* gt_b = (const float*)d_in[10];
    const float* gp_w = (const float*)d_in[11];
    const float* gp_b = (const float*)d_in[12];
    float* out = (float*)d_out;

    // Workspace layout (byte offsets, 256-aligned)
    char* ws = (char*)d_ws;
    size_t off = 0;
    auto alloc = [&](size_t bytes) {
        char* p = ws + off;
        off = (off + bytes + 255) & ~size_t(255);
        return p;
    };
    int*   nbr       = (int*)  alloc((size_t)NN * EE * sizeof(int));
    float* p_theta   = (float*)alloc((size_t)NN * DS * sizeof(float));
    float* p_phi     = (float*)alloc((size_t)NN * DS * sizeof(float));
    float* f_p       = (float*)alloc((size_t)NN * EE * sizeof(float));
    float* colnorm_p = (float*)alloc((size_t)EE * CPAD * sizeof(float));
    float* colnorm_f = (float*)alloc((size_t)3 * BB * EE * CPAD * sizeof(float));
    float* h         = (float*)alloc((size_t)BB * NN * CC * sizeof(float));
    float* T         = (float*)alloc((size_t)BB * NN * DS * sizeof(float));
    float* P         = (float*)alloc((size_t)BB * NN * DS * sizeof(float));
    float* Gx        = (float*)alloc((size_t)BB * NN * DS * sizeof(float));
    float* f         = (float*)alloc((size_t)BB * NN * EE * sizeof(float));
    (void)ws_size; (void)in_sizes; (void)n_in; (void)out_size;

    k_setup<<<512, 256, 0, stream>>>(x, gt_w, gt_b, gp_w, gp_b, nbr,
                                     p_theta, p_phi, colnorm_p, colnorm_f, h);
    for (int r = 0; r < 3; ++r) {
        float* cn = colnorm_f + (size_t)r * BB * EE * CPAD;
        // round 0 carries the one-time geo f_p blocks (768..1023)
        int nblk = (r == 0) ? 1024 : 768;
        k_proj<<<nblk, 256, 0, stream>>>(h, th_w, th_b, ph_w, ph_b, G_w, G_b,
                                         T, P, Gx, nbr, p_theta, p_phi,
                                         f_p, colnorm_p);
        k_f<<<dim3(256, 2, BB), 256, 0, stream>>>(nbr, T, P, f, cn);
        if (r < 2)
            k_attn<0><<<512, 256, 0, stream>>>(nbr, f, f_p, colnorm_p, cn, Gx,
                                               r_w, r_b, h, out);
        else
            k_attn<1><<<512, 256, 0, stream>>>(nbr, f, f_p, colnorm_p, cn, Gx,
                                               r_w, r_b, h, out);
    }
}

// Round 11
// 229.337 us; speedup vs baseline: 1.0774x; 1.0774x over previous
//
#include <hip/hip_runtime.h>
#include <math.h>

// Problem constants
#define BB 2
#define CC 128
#define NN 4096            // D*H*W = 16*16*16
#define EE 46              // 16 + 15 + 15 neighbors
#define EH 23              // EE/2 per e-half block
#define DS 64              // DSIM = PSIM = GDIM = 64
#define CPAD 16            // dwords per colnorm counter (one 64B line each)

// ===========================================================================
// Setup: zero colnorms, neighbor table, geo projections, h transpose.
// grid 512 x 256.
__global__ __launch_bounds__(256) void k_setup(
    const float* __restrict__ x,
    const float* __restrict__ gt_w, const float* __restrict__ gt_b,
    const float* __restrict__ gp_w, const float* __restrict__ gp_b,
    int* __restrict__ nbr, float* __restrict__ p_theta, float* __restrict__ p_phi,
    float* __restrict__ colnorm_p, float* __restrict__ colnorm_f,
    float* __restrict__ h)
{
    __shared__ float xs[32 * 65];
    const int t = threadIdx.x, bid = blockIdx.x;
    const int gtid = bid * 256 + t;

    if (gtid < EE * CPAD) colnorm_p[gtid] = 0.f;
    if (gtid < 3 * BB * EE * CPAD) colnorm_f[gtid] = 0.f;

    if (gtid < NN) {   // sorted 3-way merge of axis neighbor lists
        int n = gtid;
        int i = n >> 8, j = (n >> 4) & 15, k = n & 15;
        int ia = 0, ib = 0, ic = 0;
        for (int e = 0; e < EE; ++e) {
            int va = (ia < 16) ? ia * 256 + j * 16 + k : 0x7fffffff;
            int jb = ib + (ib >= j ? 1 : 0);
            int vb = (ib < 15) ? i * 256 + jb * 16 + k : 0x7fffffff;
            int kc = ic + (ic >= k ? 1 : 0);
            int vc = (ic < 15) ? i * 256 + j * 16 + kc : 0x7fffffff;
            int v;
            if (va < vb && va < vc)      { v = va; ++ia; }
            else if (vb < vc)            { v = vb; ++ib; }
            else                         { v = vc; ++ic; }
            nbr[n * EE + e] = v;
        }
    }
    for (int idx = gtid; idx < NN * DS; idx += 512 * 256) {
        int n = idx >> 6, s = idx & 63;
        int i = n >> 8, j = (n >> 4) & 15, k = n & 15;
        float p0 = i * (1.f / 15.f) - 0.5f;
        float p1 = j * (1.f / 15.f) - 0.5f;
        float p2 = k * (1.f / 15.f) - 0.5f;
        p_theta[idx] = p0 * gt_w[s * 3] + p1 * gt_w[s * 3 + 1] + p2 * gt_w[s * 3 + 2] + gt_b[s];
        p_phi[idx]   = p0 * gp_w[s * 3] + p1 * gp_w[s * 3 + 1] + p2 * gp_w[s * 3 + 2] + gp_b[s];
    }
    {   // h[b][n][c] = x[b][c][n], one 64n x 32c tile per block
        int n0 = (bid & 63) * 64, c0 = ((bid >> 6) & 3) * 32, b = bid >> 8;
        for (int q = t; q < 2048; q += 256) {
            int cl = q >> 6, nl = q & 63;
            xs[cl * 65 + nl] = x[(size_t)(b * CC + c0 + cl) * NN + n0 + nl];
        }
        __syncthreads();
        for (int q = t; q < 2048; q += 256) {
            int nl = q >> 5, cl = q & 31;
            h[(size_t)(b * NN + n0 + nl) * CC + c0 + cl] = xs[cl * 65 + nl];
        }
    }
}

// ===========================================================================
// proj: [8192x128]x[128x192]^T GEMM. 32-row x 64-col tiles, BOTH operands
// LDS-staged (48 KB -> 3 blocks/CU), XOR-swizzled, 2x4 register blocking.
// Blocks >=768 (round-0 launch only): one-time geo f_p dots + colnorm_p.
__global__ __launch_bounds__(256) void k_proj(
    const float* __restrict__ h,
    const float* __restrict__ th_w, const float* __restrict__ th_b,
    const float* __restrict__ ph_w, const float* __restrict__ ph_b,
    const float* __restrict__ G_w,  const float* __restrict__ G_b,
    float* __restrict__ T, float* __restrict__ P, float* __restrict__ Gx,
    const int* __restrict__ nbr,
    const float* __restrict__ p_theta, const float* __restrict__ p_phi,
    float* __restrict__ f_p, float* __restrict__ colnorm_p)
{
    __shared__ __align__(16) float smf[12288];   // 48 KB
    const int t = threadIdx.x;
    if (blockIdx.x < 768) {
        const int row0 = (blockIdx.x & 255) * 32;
        const int cgp = blockIdx.x >> 8;
        const float* w    = cgp == 0 ? th_w : cgp == 1 ? ph_w : G_w;
        const float* bias = cgp == 0 ? th_b : cgp == 1 ? ph_b : G_b;
        float* o          = cgp == 0 ? T    : cgp == 1 ? P    : Gx;
        float4* hs4 = (float4*)smf;              // [32][32] f4, XOR-swizzled
        float4* ws4 = (float4*)smf + 1024;       // [64][32] f4, XOR-swizzled
        const float4* h4 = (const float4*)h;
        const float4* w4 = (const float4*)w;
        for (int q = t; q < 1024; q += 256) {
            int row = q >> 5, kc = q & 31;
            hs4[row * 32 + (kc ^ row)] = h4[(size_t)(row0 + row) * 32 + kc];
        }
        for (int q = t; q < 2048; q += 256) {
            int row = q >> 5, kc = q & 31;
            ws4[row * 32 + (kc ^ (row & 31))] = w4[q];
        }
        __syncthreads();
        const int rt = t >> 4, m = t & 15;       // rows 2rt,2rt+1; cols m+16i
        float acc[2][4] = {{0, 0, 0, 0}, {0, 0, 0, 0}};
        for (int kc = 0; kc < 32; ++kc) {
            float4 a0 = hs4[(2 * rt) * 32 + (kc ^ (2 * rt))];
            float4 a1 = hs4[(2 * rt + 1) * 32 + (kc ^ (2 * rt + 1))];
            float4 wv[4];
#pragma unroll
            for (int i = 0; i < 4; ++i) {
                int c = m + 16 * i;
                wv[i] = ws4[c * 32 + (kc ^ (c & 31))];
            }
#pragma unroll
            for (int i = 0; i < 4; ++i) {
                acc[0][i] += a0.x * wv[i].x + a0.y * wv[i].y
                           + a0.z * wv[i].z + a0.w * wv[i].w;
                acc[1][i] += a1.x * wv[i].x + a1.y * wv[i].y
                           + a1.z * wv[i].z + a1.w * wv[i].w;
            }
        }
#pragma unroll
        for (int i = 0; i < 4; ++i) {
            float bv = bias[m + 16 * i];
#pragma unroll
            for (int rr = 0; rr < 2; ++rr)
                o[(size_t)(row0 + 2 * rt + rr) * DS + m + 16 * i] = acc[rr][i] + bv;
        }
    } else {
        // geo f_p: tile = blockIdx.x - 768 (b implicit 0, batch-identical)
        const int tile = blockIdx.x - 768;
        float4* ts4 = (float4*)smf;          // [16][17] f4  (dw 0..1087)
        int*    nbs = (int*)(smf + 1088);    // 736 ints
        float*  fvs = smf + 1824;            // 736 floats
        {
            int node = t >> 4, kc = t & 15;
            ts4[node * 17 + kc] =
                ((const float4*)p_theta)[(size_t)(tile * 16 + node) * 16 + kc];
        }
        for (int i2 = t; i2 < 16 * EE; i2 += 256) nbs[i2] = nbr[tile * 16 * EE + i2];
        __syncthreads();
        const int g = t >> 4, kc = t & 15;
        const float4 av = ts4[g * 17 + kc];
        const float4* P4 = (const float4*)p_phi;
        for (int e = 0; e < EE; ++e) {
            int m = nbs[g * EE + e];
            float4 p = P4[(size_t)m * 16 + kc];
            float v = av.x * p.x + av.y * p.y + av.z * p.z + av.w * p.w;
            v += __shfl_xor(v, 1);
            v += __shfl_xor(v, 2);
            v += __shfl_xor(v, 4);
            v += __shfl_xor(v, 8);
            if (kc == 0) {
                f_p[(size_t)(tile * 16 + g) * EE + e] = v;
                fvs[e * 16 + g] = v;
            }
        }
        __syncthreads();
        if (t < EE) {
            float s = 0.f;
#pragma unroll
            for (int q = 0; q < 16; ++q) { float v = fvs[t * 16 + q]; s += v * v; }
            atomicAdd(colnorm_p + t * CPAD, s);
        }
    }
}

// ===========================================================================
// k_f: f[b][n][e] = dot64(T[b,n], P[b,nbr[n,e]]) for one (tile, e-half, b).
// grid (256, 2, BB) = 1024 blocks. 16 groups of 16 lanes: group = node,
// lane = float4 chunk (coalesced 256 B row per gather).
__global__ __launch_bounds__(256) void k_f(
    const int* __restrict__ nbr,
    const float* __restrict__ T, const float* __restrict__ P,
    float* __restrict__ f, float* __restrict__ colnorm)
{
    __shared__ __align__(16) float smf[2560];
    float4* ts4 = (float4*)smf;            // [16][17] f4  (dw 0..1087)
    int*    nbs = (int*)(smf + 1088);      // 736 ints
    float*  fvs = smf + 1824;              // [EH][16] floats

    const int t = threadIdx.x;
    const int tile = blockIdx.x, half = blockIdx.y, b = blockIdx.z;
    const int n0 = tile * 16, e0 = half * EH;
    {
        int node = t >> 4, kc = t & 15;
        ts4[node * 17 + kc] =
            ((const float4*)T)[(size_t)(b * NN + n0 + node) * 16 + kc];
    }
    for (int i2 = t; i2 < 16 * EE; i2 += 256) nbs[i2] = nbr[n0 * EE + i2];
    __syncthreads();

    const int g = t >> 4, kc = t & 15;
    const float4 av = ts4[g * 17 + kc];
    const float4* P4 = (const float4*)P;
    for (int ee = 0; ee < EH; ++ee) {
        int m = nbs[g * EE + e0 + ee];
        float4 p = P4[((size_t)b * NN + m) * 16 + kc];
        float v = av.x * p.x + av.y * p.y + av.z * p.z + av.w * p.w;
        v += __shfl_xor(v, 1);
        v += __shfl_xor(v, 2);
        v += __shfl_xor(v, 4);
        v += __shfl_xor(v, 8);
        if (kc == 0) fvs[ee * 16 + g] = v;
    }
    __syncthreads();

    for (int i = t; i < 16 * EH; i += 256) {
        int nl = i / EH, ee = i - nl * EH;
        f[(size_t)(b * NN + n0 + nl) * EE + e0 + ee] = fvs[ee * 16 + nl];
    }
    if (t < EH) {
        float s = 0.f;
#pragma unroll
        for (int q = 0; q < 16; ++q) { float v = fvs[t * 16 + q]; s += v * v; }
        atomicAdd(colnorm + (b * EE + e0 + t) * CPAD, s);
    }
}

// ===========================================================================
// k_gather: softmax + Gx gather ONLY (no r_w staging, no epilogue).
// Per (b, 8-node tile), grid 1024, ~3 KB LDS -> high occupancy. Each wave
// owns 2 nodes; gather loop unrolled with 4 independent load streams;
// y written straight from registers (coalesced 256 B rows).
__global__ __launch_bounds__(256) void k_gather(
    const int* __restrict__ nbr,
    const float* __restrict__ f, const float* __restrict__ f_p,
    const float* __restrict__ colnorm_p, const float* __restrict__ colnorm_f,
    const float* __restrict__ Gx, float* __restrict__ y)
{
    __shared__ __align__(16) float smf[800];
    float* ats = smf;                      // [8][48]  (dw 0..383)
    int*   nbs = (int*)(smf + 384);        // [8][46] ints

    const int t = threadIdx.x;
    const int u = blockIdx.x;              // 0..1023
    const int b = u >> 9, tile = u & 511, n0 = tile * 8;

    for (int i2 = t; i2 < 8 * EE; i2 += 256) nbs[i2] = nbr[(size_t)n0 * EE + i2];
    __syncthreads();

    const int wv = t >> 6, l = t & 63;
    float nf_inv = 0.f, np_inv = 0.f;
    if (l < EE) {
        nf_inv = 1.f / (1e-6f + sqrtf(colnorm_f[(b * EE + l) * CPAD]));
        np_inv = 1.f / (1e-6f + sqrtf(colnorm_p[l * CPAD]));
    }
    for (int ii = 0; ii < 2; ++ii) {
        int nl = wv * 2 + ii;
        int n = n0 + nl;
        float fvv = -INFINITY;
        if (l < EE) {
            float fpv = f_p[(size_t)n * EE + l] * np_inv;
            fpv = fpv > 0.f ? fpv : 0.f;
            fvv = f[(size_t)(b * NN + n) * EE + l] * nf_inv + fpv;
        }
        float mx = fvv;
        for (int o = 32; o; o >>= 1) mx = fmaxf(mx, __shfl_down(mx, o));
        mx = __shfl(mx, 0);
        float ex = (l < EE) ? expf(fvv - mx) : 0.f;
        float sm = ex;
        for (int o = 32; o; o >>= 1) sm += __shfl_down(sm, o);
        sm = __shfl(sm, 0);
        if (l < EE) ats[nl * 48 + l] = ex / sm;
    }
    __syncthreads();

    const float* Gb = Gx + (size_t)b * NN * DS;
    const int na = wv * 2, nc = na + 1;
    float ya0 = 0.f, ya1 = 0.f, yc0 = 0.f, yc1 = 0.f;
#pragma unroll
    for (int e = 0; e < EE; e += 2) {
        float a0 = ats[na * 48 + e], a1 = ats[na * 48 + e + 1];
        float c0 = ats[nc * 48 + e], c1 = ats[nc * 48 + e + 1];
        int   m0 = nbs[na * EE + e], m1 = nbs[na * EE + e + 1];
        int   q0 = nbs[nc * EE + e], q1 = nbs[nc * EE + e + 1];
        ya0 += a0 * Gb[(size_t)m0 * DS + l];
        ya1 += a1 * Gb[(size_t)m1 * DS + l];
        yc0 += c0 * Gb[(size_t)q0 * DS + l];
        yc1 += c1 * Gb[(size_t)q1 * DS + l];
    }
    y[(size_t)(b * NN + n0 + na) * DS + l] = ya0 + ya1;
    y[(size_t)(b * NN + n0 + nc) * DS + l] = yc0 + yc1;
}

// ===========================================================================
// k_epi: delta[8192][128] = y[8192][64] @ r_w[128][64]^T + r_b + h (residual).
// grid (256 row-tiles, 2 col-halves). y-tile + rw-half LDS-staged with
// padded stride 17 (2-way bank aliasing = free). 2x4 register blocking.
// LAST=1: transpose through LDS -> out stores 128 B-contiguous.
template <int LAST>
__global__ __launch_bounds__(256) void k_epi(
    const float* __restrict__ y, const float* __restrict__ r_w,
    const float* __restrict__ r_b,
    float* __restrict__ h, float* __restrict__ out)
{
    __shared__ __align__(16) float smf[6528];    // 26112 B
    float4* ys4  = (float4*)smf;                 // [32][17] f4 (dw 0..2175)
    float4* rws4 = (float4*)smf + 544;           // [64][17] f4 (dw 2176..6527)
    float*  dls  = smf;                          // LAST: reuse as [32][68]

    const int t = threadIdx.x;
    const int rt0 = blockIdx.x * 32;             // global row (b*NN+n)
    const int c0 = blockIdx.y * 64;
    const float4* y4  = (const float4*)y;
    const float4* rw4 = (const float4*)r_w;
    for (int q = t; q < 512; q += 256) {
        int row = q >> 4, kc = q & 15;
        ys4[row * 17 + kc] = y4[(size_t)(rt0 + row) * 16 + kc];
    }
    for (int q = t; q < 1024; q += 256) {
        int row = q >> 4, kc = q & 15;
        rws4[row * 17 + kc] = rw4[(size_t)(c0 + row) * 16 + kc];
    }
    __syncthreads();

    const int rt = t >> 4, m = t & 15;           // rows 2rt,2rt+1; cols m+16i
    float acc[2][4] = {{0, 0, 0, 0}, {0, 0, 0, 0}};
    for (int kc = 0; kc < 16; ++kc) {
        float4 a0 = ys4[(2 * rt) * 17 + kc];
        float4 a1 = ys4[(2 * rt + 1) * 17 + kc];
        float4 wv[4];
#pragma unroll
        for (int i = 0; i < 4; ++i)
            wv[i] = rws4[(m + 16 * i) * 17 + kc];
#pragma unroll
        for (int i = 0; i < 4; ++i) {
            acc[0][i] += a0.x * wv[i].x + a0.y * wv[i].y
                       + a0.z * wv[i].z + a0.w * wv[i].w;
            acc[1][i] += a1.x * wv[i].x + a1.y * wv[i].y
                       + a1.z * wv[i].z + a1.w * wv[i].w;
        }
    }

    if (!LAST) {
#pragma unroll
        for (int rr = 0; rr < 2; ++rr) {
            size_t r = (size_t)rt0 + 2 * rt + rr;
#pragma unroll
            for (int i = 0; i < 4; ++i) {
                int c = c0 + m + 16 * i;
                h[r * CC + c] += acc[rr][i] + r_b[c];
            }
        }
    } else {
        // residual + bias into LDS tile, then contiguous transposed stores
        float res[2][4];
#pragma unroll
        for (int rr = 0; rr < 2; ++rr) {
            size_t r = (size_t)rt0 + 2 * rt + rr;
#pragma unroll
            for (int i = 0; i < 4; ++i) {
                int c = c0 + m + 16 * i;
                res[rr][i] = h[r * CC + c] + acc[rr][i] + r_b[c];
            }
        }
        __syncthreads();                         // done reading ys4 region
#pragma unroll
        for (int rr = 0; rr < 2; ++rr)
#pragma unroll
            for (int i = 0; i < 4; ++i)
                dls[(2 * rt + rr) * 68 + m + 16 * i] = res[rr][i];
        __syncthreads();
        const int b = rt0 >> 12, n0g = rt0 & (NN - 1);
        for (int q = t; q < 2048; q += 256) {
            int cl = q >> 5, nl = q & 31;
            out[(size_t)(b * CC + c0 + cl) * NN + n0g + nl] = dls[nl * 68 + cl];
        }
    }
}

// ===========================================================================
extern "C" void kernel_launch(void* const* d_in, const int* in_sizes, int n_in,
                              void* d_out, int out_size, void* d_ws, size_t ws_size,
                              hipStream_t stream) {
    const float* x    = (const float*)d_in[0];
    const float* G_w  = (const float*)d_in[1];
    const float* G_b  = (const float*)d_in[2];
    const float* th_w = (const float*)d_in[3];
    const float* th_b = (const float*)d_in[4];
    const float* ph_w = (const float*)d_in[5];
    const float* ph_b = (const float*)d_in[6];
    const float* r_w  = (const float*)d_in[7];
    const float* r_b  = (const float*)d_in[8];
    const float* gt_w = (const float*)d_in[9];
    const float* gt_b = (const float*)d_in[10];
    const float* gp_w = (const float*)d_in[11];
    const float* gp_b = (const float*)d_in[12];
    float* out = (float*)d_out;

    // Workspace layout (byte offsets, 256-aligned)
    char* ws = (char*)d_ws;
    size_t off = 0;
    auto alloc = [&](size_t bytes) {
        char* p = ws + off;
        off = (off + bytes + 255) & ~size_t(255);
        return p;
    };
    int*   nbr       = (int*)  alloc((size_t)NN * EE * sizeof(int));
    float* p_theta   = (float*)alloc((size_t)NN * DS * sizeof(float));
    float* p_phi     = (float*)alloc((size_t)NN * DS * sizeof(float));
    float* f_p       = (float*)alloc((size_t)NN * EE * sizeof(float));
    float* colnorm_p = (float*)alloc((size_t)EE * CPAD * sizeof(float));
    float* colnorm_f = (float*)alloc((size_t)3 * BB * EE * CPAD * sizeof(float));
    float* h         = (float*)alloc((size_t)BB * NN * CC * sizeof(float));
    float* T         = (float*)alloc((size_t)BB * NN * DS * sizeof(float));
    float* P         = (float*)alloc((size_t)BB * NN * DS * sizeof(float));
    float* Gx        = (float*)alloc((size_t)BB * NN * DS * sizeof(float));
    float* f         = (float*)alloc((size_t)BB * NN * EE * sizeof(float));
    float* y         = (float*)alloc((size_t)BB * NN * DS * sizeof(float));
    (void)ws_size; (void)in_sizes; (void)n_in; (void)out_size;

    k_setup<<<512, 256, 0, stream>>>(x, gt_w, gt_b, gp_w, gp_b, nbr,
                                     p_theta, p_phi, colnorm_p, colnorm_f, h);
    for (int r = 0; r < 3; ++r) {
        float* cn = colnorm_f + (size_t)r * BB * EE * CPAD;
        // round 0 carries the one-time geo f_p blocks (768..1023)
        int nblk = (r == 0) ? 1024 : 768;
        k_proj<<<nblk, 256, 0, stream>>>(h, th_w, th_b, ph_w, ph_b, G_w, G_b,
                                         T, P, Gx, nbr, p_theta, p_phi,
                                         f_p, colnorm_p);
        k_f<<<dim3(256, 2, BB), 256, 0, stream>>>(nbr, T, P, f, cn);
        k_gather<<<1024, 256, 0, stream>>>(nbr, f, f_p, colnorm_p, cn, Gx, y);
        if (r < 2)
            k_epi<0><<<dim3(256, 2), 256, 0, stream>>>(y, r_w, r_b, h, out);
        else
            k_epi<1><<<dim3(256, 2), 256, 0, stream>>>(y, r_w, r_b, h, out);
    }
}

// Round 12
// 188.600 us; speedup vs baseline: 1.3101x; 1.2160x over previous
//
#include <hip/hip_runtime.h>
#include <math.h>

// Problem constants
#define BB 2
#define CC 128
#define NN 4096            // D*H*W = 16*16*16
#define EE 46              // 16 + 15 + 15 neighbors
#define EH 23              // EE/2 per e-half block
#define DS 64              // DSIM = PSIM = GDIM = 64
#define CPAD 16            // dwords per colnorm counter (one 64B line each)

// ===========================================================================
// Setup: zero colnorms, neighbor table, geo projections, h transpose.
// grid 512 x 256.
__global__ __launch_bounds__(256) void k_setup(
    const float* __restrict__ x,
    const float* __restrict__ gt_w, const float* __restrict__ gt_b,
    const float* __restrict__ gp_w, const float* __restrict__ gp_b,
    int* __restrict__ nbr, float* __restrict__ p_theta, float* __restrict__ p_phi,
    float* __restrict__ colnorm_p, float* __restrict__ colnorm_f,
    float* __restrict__ h)
{
    __shared__ float xs[32 * 65];
    const int t = threadIdx.x, bid = blockIdx.x;
    const int gtid = bid * 256 + t;

    if (gtid < EE * CPAD) colnorm_p[gtid] = 0.f;
    if (gtid < 3 * BB * EE * CPAD) colnorm_f[gtid] = 0.f;

    if (gtid < NN) {   // sorted 3-way merge of axis neighbor lists
        int n = gtid;
        int i = n >> 8, j = (n >> 4) & 15, k = n & 15;
        int ia = 0, ib = 0, ic = 0;
        for (int e = 0; e < EE; ++e) {
            int va = (ia < 16) ? ia * 256 + j * 16 + k : 0x7fffffff;
            int jb = ib + (ib >= j ? 1 : 0);
            int vb = (ib < 15) ? i * 256 + jb * 16 + k : 0x7fffffff;
            int kc = ic + (ic >= k ? 1 : 0);
            int vc = (ic < 15) ? i * 256 + j * 16 + kc : 0x7fffffff;
            int v;
            if (va < vb && va < vc)      { v = va; ++ia; }
            else if (vb < vc)            { v = vb; ++ib; }
            else                         { v = vc; ++ic; }
            nbr[n * EE + e] = v;
        }
    }
    for (int idx = gtid; idx < NN * DS; idx += 512 * 256) {
        int n = idx >> 6, s = idx & 63;
        int i = n >> 8, j = (n >> 4) & 15, k = n & 15;
        float p0 = i * (1.f / 15.f) - 0.5f;
        float p1 = j * (1.f / 15.f) - 0.5f;
        float p2 = k * (1.f / 15.f) - 0.5f;
        p_theta[idx] = p0 * gt_w[s * 3] + p1 * gt_w[s * 3 + 1] + p2 * gt_w[s * 3 + 2] + gt_b[s];
        p_phi[idx]   = p0 * gp_w[s * 3] + p1 * gp_w[s * 3 + 1] + p2 * gp_w[s * 3 + 2] + gp_b[s];
    }
    {   // h[b][n][c] = x[b][c][n], one 64n x 32c tile per block
        int n0 = (bid & 63) * 64, c0 = ((bid >> 6) & 3) * 32, b = bid >> 8;
        for (int q = t; q < 2048; q += 256) {
            int cl = q >> 6, nl = q & 63;
            xs[cl * 65 + nl] = x[(size_t)(b * CC + c0 + cl) * NN + n0 + nl];
        }
        __syncthreads();
        for (int q = t; q < 2048; q += 256) {
            int nl = q >> 5, cl = q & 31;
            h[(size_t)(b * NN + n0 + nl) * CC + c0 + cl] = xs[cl * 65 + nl];
        }
    }
}

// ===========================================================================
// proj: [8192x128]x[128x192]^T GEMM. 32-row x 64-col tiles, BOTH operands
// LDS-staged (48 KB -> 3 blocks/CU), XOR-swizzled, 2x4 register blocking.
// Blocks >=768 (round-0 launch only): one-time geo f_p dots + colnorm_p.
__global__ __launch_bounds__(256) void k_proj(
    const float* __restrict__ h,
    const float* __restrict__ th_w, const float* __restrict__ th_b,
    const float* __restrict__ ph_w, const float* __restrict__ ph_b,
    const float* __restrict__ G_w,  const float* __restrict__ G_b,
    float* __restrict__ T, float* __restrict__ P, float* __restrict__ Gx,
    const int* __restrict__ nbr,
    const float* __restrict__ p_theta, const float* __restrict__ p_phi,
    float* __restrict__ f_p, float* __restrict__ colnorm_p)
{
    __shared__ __align__(16) float smf[12288];   // 48 KB
    const int t = threadIdx.x;
    if (blockIdx.x < 768) {
        const int row0 = (blockIdx.x & 255) * 32;
        const int cgp = blockIdx.x >> 8;
        const float* w    = cgp == 0 ? th_w : cgp == 1 ? ph_w : G_w;
        const float* bias = cgp == 0 ? th_b : cgp == 1 ? ph_b : G_b;
        float* o          = cgp == 0 ? T    : cgp == 1 ? P    : Gx;
        float4* hs4 = (float4*)smf;              // [32][32] f4, XOR-swizzled
        float4* ws4 = (float4*)smf + 1024;       // [64][32] f4, XOR-swizzled
        const float4* h4 = (const float4*)h;
        const float4* w4 = (const float4*)w;
        for (int q = t; q < 1024; q += 256) {
            int row = q >> 5, kc = q & 31;
            hs4[row * 32 + (kc ^ row)] = h4[(size_t)(row0 + row) * 32 + kc];
        }
        for (int q = t; q < 2048; q += 256) {
            int row = q >> 5, kc = q & 31;
            ws4[row * 32 + (kc ^ (row & 31))] = w4[q];
        }
        __syncthreads();
        const int rt = t >> 4, m = t & 15;       // rows 2rt,2rt+1; cols m+16i
        float acc[2][4] = {{0, 0, 0, 0}, {0, 0, 0, 0}};
        for (int kc = 0; kc < 32; ++kc) {
            float4 a0 = hs4[(2 * rt) * 32 + (kc ^ (2 * rt))];
            float4 a1 = hs4[(2 * rt + 1) * 32 + (kc ^ (2 * rt + 1))];
            float4 wv[4];
#pragma unroll
            for (int i = 0; i < 4; ++i) {
                int c = m + 16 * i;
                wv[i] = ws4[c * 32 + (kc ^ (c & 31))];
            }
#pragma unroll
            for (int i = 0; i < 4; ++i) {
                acc[0][i] += a0.x * wv[i].x + a0.y * wv[i].y
                           + a0.z * wv[i].z + a0.w * wv[i].w;
                acc[1][i] += a1.x * wv[i].x + a1.y * wv[i].y
                           + a1.z * wv[i].z + a1.w * wv[i].w;
            }
        }
#pragma unroll
        for (int i = 0; i < 4; ++i) {
            float bv = bias[m + 16 * i];
#pragma unroll
            for (int rr = 0; rr < 2; ++rr)
                o[(size_t)(row0 + 2 * rt + rr) * DS + m + 16 * i] = acc[rr][i] + bv;
        }
    } else {
        // geo f_p: tile = blockIdx.x - 768 (b implicit 0, batch-identical)
        const int tile = blockIdx.x - 768;
        float4* ts4 = (float4*)smf;          // [16][17] f4  (dw 0..1087)
        int*    nbs = (int*)(smf + 1088);    // 736 ints
        float*  fvs = smf + 1824;            // 736 floats
        {
            int node = t >> 4, kc = t & 15;
            ts4[node * 17 + kc] =
                ((const float4*)p_theta)[(size_t)(tile * 16 + node) * 16 + kc];
        }
        for (int i2 = t; i2 < 16 * EE; i2 += 256) nbs[i2] = nbr[tile * 16 * EE + i2];
        __syncthreads();
        const int g = t >> 4, kc = t & 15;
        const float4 av = ts4[g * 17 + kc];
        const float4* P4 = (const float4*)p_phi;
        for (int e = 0; e < EE; ++e) {
            int m = nbs[g * EE + e];
            float4 p = P4[(size_t)m * 16 + kc];
            float v = av.x * p.x + av.y * p.y + av.z * p.z + av.w * p.w;
            v += __shfl_xor(v, 1);
            v += __shfl_xor(v, 2);
            v += __shfl_xor(v, 4);
            v += __shfl_xor(v, 8);
            if (kc == 0) {
                f_p[(size_t)(tile * 16 + g) * EE + e] = v;
                fvs[e * 16 + g] = v;
            }
        }
        __syncthreads();
        if (t < EE) {
            float s = 0.f;
#pragma unroll
            for (int q = 0; q < 16; ++q) { float v = fvs[t * 16 + q]; s += v * v; }
            atomicAdd(colnorm_p + t * CPAD, s);
        }
    }
}

// ===========================================================================
// k_f: f[b][n][e] = dot64(T[b,n], P[b,nbr[n,e]]) for one (tile, e-half, b).
// grid (256, 2, BB) = 1024 blocks. 16 groups of 16 lanes: group = node,
// lane = float4 chunk (coalesced 256 B row per gather).
__global__ __launch_bounds__(256) void k_f(
    const int* __restrict__ nbr,
    const float* __restrict__ T, const float* __restrict__ P,
    float* __restrict__ f, float* __restrict__ colnorm)
{
    __shared__ __align__(16) float smf[2560];
    float4* ts4 = (float4*)smf;            // [16][17] f4  (dw 0..1087)
    int*    nbs = (int*)(smf + 1088);      // 736 ints
    float*  fvs = smf + 1824;              // [EH][16] floats

    const int t = threadIdx.x;
    const int tile = blockIdx.x, half = blockIdx.y, b = blockIdx.z;
    const int n0 = tile * 16, e0 = half * EH;
    {
        int node = t >> 4, kc = t & 15;
        ts4[node * 17 + kc] =
            ((const float4*)T)[(size_t)(b * NN + n0 + node) * 16 + kc];
    }
    for (int i2 = t; i2 < 16 * EE; i2 += 256) nbs[i2] = nbr[n0 * EE + i2];
    __syncthreads();

    const int g = t >> 4, kc = t & 15;
    const float4 av = ts4[g * 17 + kc];
    const float4* P4 = (const float4*)P;
    for (int ee = 0; ee < EH; ++ee) {
        int m = nbs[g * EE + e0 + ee];
        float4 p = P4[((size_t)b * NN + m) * 16 + kc];
        float v = av.x * p.x + av.y * p.y + av.z * p.z + av.w * p.w;
        v += __shfl_xor(v, 1);
        v += __shfl_xor(v, 2);
        v += __shfl_xor(v, 4);
        v += __shfl_xor(v, 8);
        if (kc == 0) fvs[ee * 16 + g] = v;
    }
    __syncthreads();

    for (int i = t; i < 16 * EH; i += 256) {
        int nl = i / EH, ee = i - nl * EH;
        f[(size_t)(b * NN + n0 + nl) * EE + e0 + ee] = fvs[ee * 16 + nl];
    }
    if (t < EH) {
        float s = 0.f;
#pragma unroll
        for (int q = 0; q < 16; ++q) { float v = fvs[t * 16 + q]; s += v * v; }
        atomicAdd(colnorm + (b * EE + e0 + t) * CPAD, s);
    }
}

// ===========================================================================
// k_agg: axis-decomposed dense aggregation. Neighbors of node n are 3 axis
// lines; per (axis, line, b) block: stage the line's 16 G rows ONCE (4 KB
// coalesced), run softmax for the line's 16 nodes (identical sorted-space
// numerics), classify each sorted neighbor to (axis,slot) via m^n nibble
// test, scatter this axis's weights into a 16x16 LDS matrix, then dense
// 16x16x64 matmul. Replaces the 46-way gather (96 MB L2/L3 traffic) with
// ~12 MB dense reads. y partials per axis summed in k_epi.
__device__ __forceinline__ int axis_node(int axis, int line, int s) {
    if (axis == 0) return s * 256 + line;                           // D: line=(j,k)
    if (axis == 1) return (line >> 4) * 256 + s * 16 + (line & 15); // H: line=(i,k)
    return line * 16 + s;                                           // W: line=(i,j)
}

__global__ __launch_bounds__(256) void k_agg(
    const int* __restrict__ nbr,
    const float* __restrict__ f, const float* __restrict__ f_p,
    const float* __restrict__ colnorm_p, const float* __restrict__ colnorm_f,
    const float* __restrict__ Gx, float* __restrict__ y)
{
    __shared__ __align__(16) float Gl[16 * 64];   // 4 KB
    __shared__ float wmat[256];                   // [16 nodes][16 slots]
    __shared__ float nf[64], np[64];

    const int t = threadIdx.x;
    const int line = blockIdx.x, axis = blockIdx.y, b = blockIdx.z;

    if (t < EE) {
        nf[t] = 1.f / (1e-6f + sqrtf(colnorm_f[(b * EE + t) * CPAD]));
        np[t] = 1.f / (1e-6f + sqrtf(colnorm_p[t * CPAD]));
    }
    wmat[t] = 0.f;
    {
        int s = t >> 4, c4 = t & 15;
        int nrow = axis_node(axis, line, s);
        ((float4*)Gl)[s * 16 + c4] =
            ((const float4*)Gx)[((size_t)b * NN + nrow) * 16 + c4];
    }
    __syncthreads();

    const int wv = t >> 6, l = t & 63;
    for (int ii = 0; ii < 4; ++ii) {
        int sn = wv * 4 + ii;
        int n = axis_node(axis, line, sn);
        float fvv = -INFINITY; int m = 0;
        if (l < EE) {
            float fpv = f_p[(size_t)n * EE + l] * np[l];
            fpv = fpv > 0.f ? fpv : 0.f;
            fvv = f[(size_t)(b * NN + n) * EE + l] * nf[l] + fpv;
            m = nbr[n * EE + l];
        }
        float mx = fvv;
        for (int o = 32; o; o >>= 1) mx = fmaxf(mx, __shfl_down(mx, o));
        mx = __shfl(mx, 0);
        float ex = (l < EE) ? expf(fvv - mx) : 0.f;
        float sm = ex;
        for (int o = 32; o; o >>= 1) sm += __shfl_down(sm, o);
        sm = __shfl(sm, 0);
        if (l < EE) {
            float at = ex / sm;
            int x = m ^ n;
            int ax, slot;
            if (x == 0)       { ax = 0; slot = n >> 8; }         // self: D list
            else if (x < 16)  { ax = 2; slot = m & 15; }         // W
            else if (x < 256) { ax = 1; slot = (m >> 4) & 15; }  // H
            else              { ax = 0; slot = m >> 8; }         // D
            if (ax == axis) wmat[sn * 16 + slot] = at;
        }
    }
    __syncthreads();

    // dense 16x16x64: wave wv handles nodes wv*4..wv*4+3, lane l = dim
    float acc[4] = {0.f, 0.f, 0.f, 0.f};
    for (int s = 0; s < 16; ++s) {
        float gv = Gl[s * 64 + l];
        acc[0] += wmat[(wv * 4 + 0) * 16 + s] * gv;
        acc[1] += wmat[(wv * 4 + 1) * 16 + s] * gv;
        acc[2] += wmat[(wv * 4 + 2) * 16 + s] * gv;
        acc[3] += wmat[(wv * 4 + 3) * 16 + s] * gv;
    }
    float* ya = y + ((size_t)axis * BB + b) * NN * DS;
#pragma unroll
    for (int kk = 0; kk < 4; ++kk) {
        int n = axis_node(axis, line, wv * 4 + kk);
        ya[(size_t)n * DS + l] = acc[kk];
    }
}

// ===========================================================================
// k_epi: delta[8192][128] = y[8192][64] @ r_w[128][64]^T + r_b + h (residual),
// where y = y_D + y_H + y_W (axis partials summed during staging).
// grid (256 row-tiles, 2 col-halves). Padded-stride LDS (2-way free).
// LAST=1: transpose through LDS -> out stores 128 B-contiguous.
template <int LAST>
__global__ __launch_bounds__(256) void k_epi(
    const float* __restrict__ y, const float* __restrict__ r_w,
    const float* __restrict__ r_b,
    float* __restrict__ h, float* __restrict__ out)
{
    __shared__ __align__(16) float smf[6528];    // 26112 B
    float4* ys4  = (float4*)smf;                 // [32][17] f4 (dw 0..2175)
    float4* rws4 = (float4*)smf + 544;           // [64][17] f4 (dw 2176..6527)
    float*  dls  = smf;                          // LAST: reuse as [32][68]

    const int t = threadIdx.x;
    const int rt0 = blockIdx.x * 32;             // global row (b*NN+n)
    const int c0 = blockIdx.y * 64;
    const float4* y4  = (const float4*)y;
    const float4* rw4 = (const float4*)r_w;
    for (int q = t; q < 512; q += 256) {
        int row = q >> 4, kc = q & 15;
        float4 a = y4[(size_t)(rt0 + row) * 16 + kc];
        float4 bb = y4[((size_t)BB * NN + rt0 + row) * 16 + kc];
        float4 c = y4[((size_t)2 * BB * NN + rt0 + row) * 16 + kc];
        float4 s;
        s.x = a.x + bb.x + c.x; s.y = a.y + bb.y + c.y;
        s.z = a.z + bb.z + c.z; s.w = a.w + bb.w + c.w;
        ys4[row * 17 + kc] = s;
    }
    for (int q = t; q < 1024; q += 256) {
        int row = q >> 4, kc = q & 15;
        rws4[row * 17 + kc] = rw4[(size_t)(c0 + row) * 16 + kc];
    }
    __syncthreads();

    const int rt = t >> 4, m = t & 15;           // rows 2rt,2rt+1; cols m+16i
    float acc[2][4] = {{0, 0, 0, 0}, {0, 0, 0, 0}};
    for (int kc = 0; kc < 16; ++kc) {
        float4 a0 = ys4[(2 * rt) * 17 + kc];
        float4 a1 = ys4[(2 * rt + 1) * 17 + kc];
        float4 wv[4];
#pragma unroll
        for (int i = 0; i < 4; ++i)
            wv[i] = rws4[(m + 16 * i) * 17 + kc];
#pragma unroll
        for (int i = 0; i < 4; ++i) {
            acc[0][i] += a0.x * wv[i].x + a0.y * wv[i].y
                       + a0.z * wv[i].z + a0.w * wv[i].w;
            acc[1][i] += a1.x * wv[i].x + a1.y * wv[i].y
                       + a1.z * wv[i].z + a1.w * wv[i].w;
        }
    }

    if (!LAST) {
#pragma unroll
        for (int rr = 0; rr < 2; ++rr) {
            size_t r = (size_t)rt0 + 2 * rt + rr;
#pragma unroll
            for (int i = 0; i < 4; ++i) {
                int c = c0 + m + 16 * i;
                h[r * CC + c] += acc[rr][i] + r_b[c];
            }
        }
    } else {
        // residual + bias into LDS tile, then contiguous transposed stores
        float res[2][4];
#pragma unroll
        for (int rr = 0; rr < 2; ++rr) {
            size_t r = (size_t)rt0 + 2 * rt + rr;
#pragma unroll
            for (int i = 0; i < 4; ++i) {
                int c = c0 + m + 16 * i;
                res[rr][i] = h[r * CC + c] + acc[rr][i] + r_b[c];
            }
        }
        __syncthreads();                         // done reading ys4 region
#pragma unroll
        for (int rr = 0; rr < 2; ++rr)
#pragma unroll
            for (int i = 0; i < 4; ++i)
                dls[(2 * rt + rr) * 68 + m + 16 * i] = res[rr][i];
        __syncthreads();
        const int b = rt0 >> 12, n0g = rt0 & (NN - 1);
        for (int q = t; q < 2048; q += 256) {
            int cl = q >> 5, nl = q & 31;
            out[(size_t)(b * CC + c0 + cl) * NN + n0g + nl] = dls[nl * 68 + cl];
        }
    }
}

// ===========================================================================
extern "C" void kernel_launch(void* const* d_in, const int* in_sizes, int n_in,
                              void* d_out, int out_size, void* d_ws, size_t ws_size,
                              hipStream_t stream) {
    const float* x    = (const float*)d_in[0];
    const float* G_w  = (const float*)d_in[1];
    const float* G_b  = (const float*)d_in[2];
    const float* th_w = (const float*)d_in[3];
    const float* th_b = (const float*)d_in[4];
    const float* ph_w = (const float*)d_in[5];
    const float* ph_b = (const float*)d_in[6];
    const float* r_w  = (const float*)d_in[7];
    const float* r_b  = (const float*)d_in[8];
    const float* gt_w = (const float*)d_in[9];
    const float* gt_b = (const float*)d_in[10];
    const float* gp_w = (const float*)d_in[11];
    const float* gp_b = (const float*)d_in[12];
    float* out = (float*)d_out;

    // Workspace layout (byte offsets, 256-aligned)
    char* ws = (char*)d_ws;
    size_t off = 0;
    auto alloc = [&](size_t bytes) {
        char* p = ws + off;
        off = (off + bytes + 255) & ~size_t(255);
        return p;
    };
    int*   nbr       = (int*)  alloc((size_t)NN * EE * sizeof(int));
    float* p_theta   = (float*)alloc((size_t)NN * DS * sizeof(float));
    float* p_phi     = (float*)alloc((size_t)NN * DS * sizeof(float));
    float* f_p       = (float*)alloc((size_t)NN * EE * sizeof(float));
    float* colnorm_p = (float*)alloc((size_t)EE * CPAD * sizeof(float));
    float* colnorm_f = (float*)alloc((size_t)3 * BB * EE * CPAD * sizeof(float));
    float* h         = (float*)alloc((size_t)BB * NN * CC * sizeof(float));
    float* T         = (float*)alloc((size_t)BB * NN * DS * sizeof(float));
    float* P         = (float*)alloc((size_t)BB * NN * DS * sizeof(float));
    float* Gx        = (float*)alloc((size_t)BB * NN * DS * sizeof(float));
    float* f         = (float*)alloc((size_t)BB * NN * EE * sizeof(float));
    float* y         = (float*)alloc((size_t)3 * BB * NN * DS * sizeof(float));
    (void)ws_size; (void)in_sizes; (void)n_in; (void)out_size;

    k_setup<<<512, 256, 0, stream>>>(x, gt_w, gt_b, gp_w, gp_b, nbr,
                                     p_theta, p_phi, colnorm_p, colnorm_f, h);
    for (int r = 0; r < 3; ++r) {
        float* cn = colnorm_f + (size_t)r * BB * EE * CPAD;
        // round 0 carries the one-time geo f_p blocks (768..1023)
        int nblk = (r == 0) ? 1024 : 768;
        k_proj<<<nblk, 256, 0, stream>>>(h, th_w, th_b, ph_w, ph_b, G_w, G_b,
                                         T, P, Gx, nbr, p_theta, p_phi,
                                         f_p, colnorm_p);
        k_f<<<dim3(256, 2, BB), 256, 0, stream>>>(nbr, T, P, f, cn);
        k_agg<<<dim3(256, 3, BB), 256, 0, stream>>>(nbr, f, f_p, colnorm_p, cn,
                                                    Gx, y);
        if (r < 2)
            k_epi<0><<<dim3(256, 2), 256, 0, stream>>>(y, r_w, r_b, h, out);
        else
            k_epi<1><<<dim3(256, 2), 256, 0, stream>>>(y, r_w, r_b, h, out);
    }
}